// Round 1
// baseline (2959.094 us; speedup 1.0000x reference)
//
#include <hip/hip_runtime.h>

#define NN 100000
#define NE 1600000
#define NEO 400000
#define HID 64
#define NL 6
#define BN_EPS 1e-5f

// ---- workspace layout (float offsets, 84MB total) ----
#define OFF_DINV 0
#define OFF_NORM 102400                 // NE floats
#define OFF_XE   (OFF_NORM + NE)        // NN*64
#define OFF_HW   (OFF_XE + NN * HID)    // NN*64
#define OFF_AGG  (OFF_HW + NN * HID)    // NN*64
#define OFF_SUM  (OFF_AGG + NN * HID)   // 128 doubles (256 floats), 8B-aligned
#define OFF_SS   (OFF_SUM + 256)        // scale[64], shift[64]

__global__ void k_init_deg(float* __restrict__ deg) {
    int i = blockIdx.x * blockDim.x + threadIdx.x;
    if (i < NN) deg[i] = 1.0f;  // self-loop
}

__global__ void k_deg_accum(const int* __restrict__ dst, float* __restrict__ deg) {
    int e = blockIdx.x * blockDim.x + threadIdx.x;
    if (e < NE) atomicAdd(&deg[dst[e]], 1.0f);
}

__global__ void k_dinv(float* __restrict__ deg) {
    int i = blockIdx.x * blockDim.x + threadIdx.x;
    if (i < NN) deg[i] = rsqrtf(deg[i]);  // deg >= 1 always
}

__global__ void k_norm(const int* __restrict__ src, const int* __restrict__ dst,
                       const float* __restrict__ dinv, float* __restrict__ nrm) {
    int e = blockIdx.x * blockDim.x + threadIdx.x;
    if (e < NE) nrm[e] = dinv[src[e]] * dinv[dst[e]];
}

// xe = x[NN,16] @ W[16,64] + b
__global__ void k_embed(const float* __restrict__ x, const float* __restrict__ W,
                        const float* __restrict__ b, float* __restrict__ xe) {
    __shared__ float Ws[16 * 64];
    __shared__ float bs[64];
    int t = threadIdx.x;
    for (int i = t; i < 16 * 64; i += 256) Ws[i] = W[i];
    if (t < 64) bs[t] = b[t];
    __syncthreads();
    int c = t & 63, r = t >> 6;
    int n0 = blockIdx.x * 64;
    for (int n = n0 + r; n < n0 + 64 && n < NN; n += 4) {
        const float* xr = x + n * 16;  // wave-uniform row -> L1 broadcast
        float acc = bs[c];
#pragma unroll
        for (int k = 0; k < 16; k++) acc = fmaf(xr[k], Ws[k * 64 + c], acc);
        xe[n * 64 + c] = acc;
    }
}

// hw = xe[NN,64] @ W[64,64]  (W + 4 node rows staged in LDS)
__global__ void k_hw(const float* __restrict__ xe, const float* __restrict__ W,
                     float* __restrict__ hw) {
    __shared__ float Ws[64 * 64];
    __shared__ float Xs[4 * 64];
    int t = threadIdx.x;
    for (int i = t; i < 64 * 64; i += 256) Ws[i] = W[i];
    int c = t & 63, r = t >> 6;
    int n0 = blockIdx.x * 64;
    __syncthreads();
    for (int i = 0; i < 16; i++) {
        int n = n0 + i * 4 + r;
        if (i) __syncthreads();
        if (n < NN) Xs[t] = xe[n * 64 + c];  // Xs[r][c], coalesced 1KB
        __syncthreads();
        if (n < NN) {
            float acc = 0.f;
#pragma unroll
            for (int k = 0; k < 64; k++)
                acc = fmaf(Xs[r * 64 + k], Ws[k * 64 + c], acc);  // bcast + 2-way (free)
            hw[n * 64 + c] = acc;
        }
    }
}

// one wave per edge, lane = channel: agg[dst][c] += hw[src][c] * norm[e]
__global__ void k_scatter(const int* __restrict__ src, const int* __restrict__ dst,
                          const float* __restrict__ nrm, const float* __restrict__ hw,
                          float* __restrict__ agg) {
    int t = threadIdx.x;
    int lane = t & 63;
    int e = blockIdx.x * 4 + (t >> 6);
    if (e < NE) {
        int s = __builtin_amdgcn_readfirstlane(src[e]);
        int d = __builtin_amdgcn_readfirstlane(dst[e]);
        float w = nrm[e];
        float v = hw[s * 64 + lane] * w;
        atomicAdd(&agg[d * 64 + lane], v);
    }
}

// fold in self-loop term, accumulate per-channel sum/sumsq (double)
__global__ void k_stats(float* __restrict__ agg, const float* __restrict__ hw,
                        const float* __restrict__ dinv, double* __restrict__ sums) {
    int t = threadIdx.x;
    int c = t & 63, r = t >> 6;
    double ls = 0.0, lq = 0.0;
    for (int n = blockIdx.x * 4 + r; n < NN; n += gridDim.x * 4) {
        float di = dinv[n];
        float v = agg[n * 64 + c] + hw[n * 64 + c] * di * di;
        agg[n * 64 + c] = v;
        ls += (double)v;
        lq += (double)v * (double)v;
    }
    __shared__ double Ss[256], Sq[256];
    Ss[t] = ls; Sq[t] = lq;
    __syncthreads();
    if (r == 0) {
        double a = Ss[c] + Ss[64 + c] + Ss[128 + c] + Ss[192 + c];
        double b = Sq[c] + Sq[64 + c] + Sq[128 + c] + Sq[192 + c];
        atomicAdd(&sums[c], a);
        atomicAdd(&sums[64 + c], b);
    }
}

// scale = gamma*rsqrt(var+eps); shift = beta - mean*scale  (conv_b cancels in BN)
__global__ void k_finalize(const double* __restrict__ sums, const float* __restrict__ gamma,
                           const float* __restrict__ beta, float* __restrict__ ss) {
    int c = threadIdx.x;  // 64 threads
    double mean = sums[c] / (double)NN;
    double var = sums[64 + c] / (double)NN - mean * mean;
    float sc = gamma[c] * rsqrtf((float)var + BN_EPS);
    ss[c] = sc;
    ss[64 + c] = beta[c] - (float)mean * sc;
}

// xe += relu(agg*scale + shift)
__global__ void k_apply(const float* __restrict__ agg, const float* __restrict__ ss,
                        float* __restrict__ xe) {
    int i = blockIdx.x * blockDim.x + threadIdx.x;
    if (i < NN * HID) {
        int c = i & 63;
        float v = fmaf(agg[i], ss[c], ss[64 + c]);
        xe[i] += fmaxf(v, 0.f);
    }
}

// out[e] = [xe[s]; xe[d]] @ fc_W + fc_b   (1 thread per edge, float4 row loads)
__global__ void k_out(const int* __restrict__ esrc, const int* __restrict__ edst,
                      const float* __restrict__ xe, const float* __restrict__ fcW,
                      const float* __restrict__ fcb, float* __restrict__ out) {
    __shared__ float Ws[256];
    __shared__ float bs[2];
    int t = threadIdx.x;
    for (int i = t; i < 256; i += 256) Ws[i] = fcW[i];
    if (t < 2) bs[t] = fcb[t];
    __syncthreads();
    int e = blockIdx.x * blockDim.x + t;
    if (e < NEO) {
        int s = esrc[e], d = edst[e];
        const float4* rs = (const float4*)(xe + s * 64);
        const float4* rd = (const float4*)(xe + d * 64);
        float a0 = bs[0], a1 = bs[1];
#pragma unroll
        for (int i = 0; i < 16; i++) {
            float4 v = rs[i];
            a0 += v.x * Ws[(i * 4 + 0) * 2] + v.y * Ws[(i * 4 + 1) * 2] +
                  v.z * Ws[(i * 4 + 2) * 2] + v.w * Ws[(i * 4 + 3) * 2];
            a1 += v.x * Ws[(i * 4 + 0) * 2 + 1] + v.y * Ws[(i * 4 + 1) * 2 + 1] +
                  v.z * Ws[(i * 4 + 2) * 2 + 1] + v.w * Ws[(i * 4 + 3) * 2 + 1];
        }
#pragma unroll
        for (int i = 0; i < 16; i++) {
            float4 v = rd[i];
            a0 += v.x * Ws[(64 + i * 4 + 0) * 2] + v.y * Ws[(64 + i * 4 + 1) * 2] +
                  v.z * Ws[(64 + i * 4 + 2) * 2] + v.w * Ws[(64 + i * 4 + 3) * 2];
            a1 += v.x * Ws[(64 + i * 4 + 0) * 2 + 1] + v.y * Ws[(64 + i * 4 + 1) * 2 + 1] +
                  v.z * Ws[(64 + i * 4 + 2) * 2 + 1] + v.w * Ws[(64 + i * 4 + 3) * 2 + 1];
        }
        out[e * 2] = a0;
        out[e * 2 + 1] = a1;
    }
}

extern "C" void kernel_launch(void* const* d_in, const int* in_sizes, int n_in,
                              void* d_out, int out_size, void* d_ws, size_t ws_size,
                              hipStream_t stream) {
    const float* x      = (const float*)d_in[0];
    const int*   ei     = (const int*)d_in[1];
    const int*   eio    = (const int*)d_in[2];
    const float* W_emb  = (const float*)d_in[3];
    const float* b_emb  = (const float*)d_in[4];
    const float* conv_W = (const float*)d_in[5];
    // d_in[6] conv_b: cancels inside BN (h - mean_h == agg - mean_agg)
    const float* bn_g   = (const float*)d_in[7];
    const float* bn_b   = (const float*)d_in[8];
    const float* fc_W   = (const float*)d_in[9];
    const float* fc_b   = (const float*)d_in[10];
    float* out = (float*)d_out;

    float* ws   = (float*)d_ws;
    float* dinv = ws + OFF_DINV;
    float* nrm  = ws + OFF_NORM;
    float* xe   = ws + OFF_XE;
    float* hw   = ws + OFF_HW;
    float* agg  = ws + OFF_AGG;
    double* sums = (double*)(ws + OFF_SUM);
    float* ss   = ws + OFF_SS;

    const int* src  = ei;
    const int* dst  = ei + NE;
    const int* esrc = eio;
    const int* edst = eio + NEO;

    k_init_deg<<<(NN + 255) / 256, 256, 0, stream>>>(dinv);
    k_deg_accum<<<(NE + 255) / 256, 256, 0, stream>>>(dst, dinv);
    k_dinv<<<(NN + 255) / 256, 256, 0, stream>>>(dinv);
    k_norm<<<(NE + 255) / 256, 256, 0, stream>>>(src, dst, dinv, nrm);
    k_embed<<<(NN + 63) / 64, 256, 0, stream>>>(x, W_emb, b_emb, xe);

    for (int l = 0; l < NL; l++) {
        k_hw<<<(NN + 63) / 64, 256, 0, stream>>>(xe, conv_W + l * 64 * 64, hw);
        hipMemsetAsync(agg, 0, (size_t)NN * HID * sizeof(float), stream);
        k_scatter<<<(NE + 3) / 4, 256, 0, stream>>>(src, dst, nrm, hw, agg);
        hipMemsetAsync(sums, 0, 128 * sizeof(double), stream);
        k_stats<<<1024, 256, 0, stream>>>(agg, hw, dinv, sums);
        k_finalize<<<1, 64, 0, stream>>>(sums, bn_g + l * 64, bn_b + l * 64, ss);
        k_apply<<<(NN * HID) / 256, 256, 0, stream>>>(agg, ss, xe);
    }

    k_out<<<(NEO + 255) / 256, 256, 0, stream>>>(esrc, edst, xe, fc_W, fc_b, out);
}

// Round 2
// 1120.292 us; speedup vs baseline: 2.6414x; 2.6414x over previous
//
#include <hip/hip_runtime.h>

#define NN 100000
#define NE 1600000
#define NEO 400000
#define HID 64
#define NL 6
#define BN_EPS 1e-5f

#define SPMM_BLOCKS 2048
#define SCAN_BS 512
#define SCAN_NB 196   // ceil(100000/512)

// ---- d_ws layout (float offsets): big arrays only, 83.2MB ----
#define OFF_ECOL 0                       // NE ints
#define OFF_XE   NE                      // NN*64 f
#define OFF_HWS  (OFF_XE + NN * HID)     // NN*64 f
#define OFF_AGG  (OFF_HWS + NN * HID)    // NN*64 f  -> end 20.8M floats

// ---- d_out head used as scratch (dead before k_out overwrites) ----
#define OD_DINV   0                      // NN f
#define OD_ROWPTR 100000                 // NN+1 ints (rounded 100352)
#define OD_CC     200352                 // NN ints (counts, then cursors)
#define OD_BSUM   300352                 // 256 ints (scan partials)
#define OD_SS     300608                 // 128 f (scale/shift)
#define OD_SUMS   300736                 // 16*128 doubles = 4096 f (8B aligned)

__global__ void k_hist(const int* __restrict__ dst, int* __restrict__ cnt) {
    int e = blockIdx.x * blockDim.x + threadIdx.x;
    if (e < NE) atomicAdd(&cnt[dst[e]], 1);
}

// per-block inclusive scan of counts -> local-exclusive rowptr + block totals; also dinv
__global__ void k_scanA(const int* __restrict__ cnt, int* __restrict__ rowptr,
                        int* __restrict__ bsum, float* __restrict__ dinv) {
    __shared__ int sh[SCAN_BS];
    int t = threadIdx.x;
    int i = blockIdx.x * SCAN_BS + t;
    int v = (i < NN) ? cnt[i] : 0;
    sh[t] = v;
    __syncthreads();
    for (int off = 1; off < SCAN_BS; off <<= 1) {
        int a = (t >= off) ? sh[t - off] : 0;
        __syncthreads();
        sh[t] += a;
        __syncthreads();
    }
    if (i < NN) {
        rowptr[i] = sh[t] - v;                       // local exclusive
        dinv[i] = rsqrtf((float)(v + 1));            // deg = in-deg + self-loop
    }
    if (t == SCAN_BS - 1) bsum[blockIdx.x] = sh[t];
}

__global__ void k_scanB(int* __restrict__ bsum) {
    __shared__ int sh[256];
    int t = threadIdx.x;
    int v = (t < SCAN_NB) ? bsum[t] : 0;
    sh[t] = v;
    __syncthreads();
    for (int off = 1; off < 256; off <<= 1) {
        int a = (t >= off) ? sh[t - off] : 0;
        __syncthreads();
        sh[t] += a;
        __syncthreads();
    }
    if (t < SCAN_NB) bsum[t] = (t == 0) ? 0 : sh[t - 1];  // exclusive block offsets
}

__global__ void k_scanC(int* __restrict__ rowptr, const int* __restrict__ bsum,
                        int* __restrict__ cursor) {
    int i = blockIdx.x * SCAN_BS + threadIdx.x;
    if (i < NN) {
        int rp = rowptr[i] + bsum[blockIdx.x];
        rowptr[i] = rp;
        cursor[i] = rp;
    }
    if (i == 0) rowptr[NN] = NE;
}

__global__ void k_build(const int* __restrict__ src, const int* __restrict__ dst,
                        int* __restrict__ cursor, int* __restrict__ ecol) {
    int e = blockIdx.x * blockDim.x + threadIdx.x;
    if (e < NE) {
        int pos = atomicAdd(&cursor[dst[e]], 1);
        ecol[pos] = src[e];
    }
}

// xe = x[NN,16] @ W[16,64] + b
__global__ void k_embed(const float* __restrict__ x, const float* __restrict__ W,
                        const float* __restrict__ b, float* __restrict__ xe) {
    __shared__ float Ws[16 * 64];
    __shared__ float bs[64];
    int t = threadIdx.x;
    for (int i = t; i < 16 * 64; i += 256) Ws[i] = W[i];
    if (t < 64) bs[t] = b[t];
    __syncthreads();
    int c = t & 63, r = t >> 6;
    int n0 = blockIdx.x * 64;
    for (int n = n0 + r; n < n0 + 64 && n < NN; n += 4) {
        const float* xr = x + n * 16;
        float acc = bs[c];
#pragma unroll
        for (int k = 0; k < 16; k++) acc = fmaf(xr[k], Ws[k * 64 + c], acc);
        xe[n * 64 + c] = acc;
    }
}

// hws = dinv[n] * (xe[NN,64] @ W[64,64]); block 0 also zeroes the stats shadows
__global__ void k_hw(const float* __restrict__ xe, const float* __restrict__ W,
                     const float* __restrict__ dinv, float* __restrict__ hws,
                     double* __restrict__ sums) {
    __shared__ float Ws[64 * 64];
    __shared__ float Xs[4 * 64];
    int t = threadIdx.x;
    if (blockIdx.x == 0) {
        for (int i = t; i < 16 * 128; i += 256) sums[i] = 0.0;
    }
    for (int i = t; i < 64 * 64; i += 256) Ws[i] = W[i];
    int c = t & 63, r = t >> 6;
    int n0 = blockIdx.x * 64;
    __syncthreads();
    for (int i = 0; i < 16; i++) {
        int n = n0 + i * 4 + r;
        if (i) __syncthreads();
        if (n < NN) Xs[t] = xe[n * 64 + c];
        __syncthreads();
        if (n < NN) {
            float acc = 0.f;
#pragma unroll
            for (int k = 0; k < 64; k++)
                acc = fmaf(Xs[r * 64 + k], Ws[k * 64 + c], acc);
            hws[n * 64 + c] = acc * dinv[n];
        }
    }
}

// agg[d] = dinv[d]*(hws[d] + sum_{s in N(d)} hws[s]); fused BN stats
__global__ void k_spmm(const int* __restrict__ rowptr, const int* __restrict__ ecol,
                       const float* __restrict__ hws, const float* __restrict__ dinv,
                       float* __restrict__ agg, double* __restrict__ sums) {
    int t = threadIdx.x, c = t & 63, r = t >> 6;
    double ls = 0.0, lq = 0.0;
    for (int row = blockIdx.x * 4 + r; row < NN; row += SPMM_BLOCKS * 4) {
        int p0 = rowptr[row], p1 = rowptr[row + 1];
        float acc = hws[row * 64 + c];
        int p = p0;
        for (; p + 4 <= p1; p += 4) {
            int s0 = ecol[p], s1 = ecol[p + 1], s2 = ecol[p + 2], s3 = ecol[p + 3];
            float v0 = hws[s0 * 64 + c];
            float v1 = hws[s1 * 64 + c];
            float v2 = hws[s2 * 64 + c];
            float v3 = hws[s3 * 64 + c];
            acc += v0; acc += v1; acc += v2; acc += v3;
        }
        for (; p < p1; p++) acc += hws[ecol[p] * 64 + c];
        float v = acc * dinv[row];
        agg[row * 64 + c] = v;
        ls += v;
        lq += (double)v * v;
    }
    __shared__ double Ss[256], Sq[256];
    Ss[t] = ls; Sq[t] = lq;
    __syncthreads();
    if (r == 0) {
        double a = Ss[c] + Ss[64 + c] + Ss[128 + c] + Ss[192 + c];
        double b = Sq[c] + Sq[64 + c] + Sq[128 + c] + Sq[192 + c];
        double* sh = sums + (blockIdx.x & 15) * 128;   // 16 shadows: low contention
        atomicAdd(&sh[c], a);
        atomicAdd(&sh[64 + c], b);
    }
}

// scale = gamma*rsqrt(var+eps); shift = beta - mean*scale (conv_b cancels in BN)
__global__ void k_finalize(const double* __restrict__ sums, const float* __restrict__ gamma,
                           const float* __restrict__ beta, float* __restrict__ ss) {
    int c = threadIdx.x;  // 64 threads
    double s = 0.0, q = 0.0;
#pragma unroll
    for (int k = 0; k < 16; k++) { s += sums[k * 128 + c]; q += sums[k * 128 + 64 + c]; }
    double mean = s / (double)NN;
    double var = q / (double)NN - mean * mean;
    float sc = gamma[c] * rsqrtf((float)var + BN_EPS);
    ss[c] = sc;
    ss[64 + c] = beta[c] - (float)mean * sc;
}

// xe += relu(agg*scale + shift)
__global__ void k_apply(const float* __restrict__ agg, const float* __restrict__ ss,
                        float* __restrict__ xe) {
    int i = blockIdx.x * blockDim.x + threadIdx.x;
    if (i < NN * HID) {
        int c = i & 63;
        float v = fmaf(agg[i], ss[c], ss[64 + c]);
        xe[i] += fmaxf(v, 0.f);
    }
}

// out[e] = [xe[s]; xe[d]] @ fc_W + fc_b
__global__ void k_out(const int* __restrict__ esrc, const int* __restrict__ edst,
                      const float* __restrict__ xe, const float* __restrict__ fcW,
                      const float* __restrict__ fcb, float* __restrict__ out) {
    __shared__ float Ws[256];
    __shared__ float bs[2];
    int t = threadIdx.x;
    for (int i = t; i < 256; i += 256) Ws[i] = fcW[i];
    if (t < 2) bs[t] = fcb[t];
    __syncthreads();
    int e = blockIdx.x * blockDim.x + t;
    if (e < NEO) {
        int s = esrc[e], d = edst[e];
        const float4* rs = (const float4*)(xe + s * 64);
        const float4* rd = (const float4*)(xe + d * 64);
        float a0 = bs[0], a1 = bs[1];
#pragma unroll
        for (int i = 0; i < 16; i++) {
            float4 v = rs[i];
            a0 += v.x * Ws[(i * 4 + 0) * 2] + v.y * Ws[(i * 4 + 1) * 2] +
                  v.z * Ws[(i * 4 + 2) * 2] + v.w * Ws[(i * 4 + 3) * 2];
            a1 += v.x * Ws[(i * 4 + 0) * 2 + 1] + v.y * Ws[(i * 4 + 1) * 2 + 1] +
                  v.z * Ws[(i * 4 + 2) * 2 + 1] + v.w * Ws[(i * 4 + 3) * 2 + 1];
        }
#pragma unroll
        for (int i = 0; i < 16; i++) {
            float4 v = rd[i];
            a0 += v.x * Ws[(64 + i * 4 + 0) * 2] + v.y * Ws[(64 + i * 4 + 1) * 2] +
                  v.z * Ws[(64 + i * 4 + 2) * 2] + v.w * Ws[(64 + i * 4 + 3) * 2];
            a1 += v.x * Ws[(64 + i * 4 + 0) * 2 + 1] + v.y * Ws[(64 + i * 4 + 1) * 2 + 1] +
                  v.z * Ws[(64 + i * 4 + 2) * 2 + 1] + v.w * Ws[(64 + i * 4 + 3) * 2 + 1];
        }
        out[e * 2] = a0;
        out[e * 2 + 1] = a1;
    }
}

extern "C" void kernel_launch(void* const* d_in, const int* in_sizes, int n_in,
                              void* d_out, int out_size, void* d_ws, size_t ws_size,
                              hipStream_t stream) {
    const float* x      = (const float*)d_in[0];
    const int*   ei     = (const int*)d_in[1];
    const int*   eio    = (const int*)d_in[2];
    const float* W_emb  = (const float*)d_in[3];
    const float* b_emb  = (const float*)d_in[4];
    const float* conv_W = (const float*)d_in[5];
    // d_in[6] conv_b: cancels inside BN
    const float* bn_g   = (const float*)d_in[7];
    const float* bn_b   = (const float*)d_in[8];
    const float* fc_W   = (const float*)d_in[9];
    const float* fc_b   = (const float*)d_in[10];
    float* out = (float*)d_out;

    float* ws  = (float*)d_ws;
    int*   ecol = (int*)(ws + OFF_ECOL);
    float* xe   = ws + OFF_XE;
    float* hws  = ws + OFF_HWS;
    float* agg  = ws + OFF_AGG;

    // small scratch in d_out head (dead before k_out overwrites all of d_out)
    float* od     = (float*)d_out;
    float* dinv   = od + OD_DINV;
    int*   rowptr = (int*)(od + OD_ROWPTR);
    int*   cc     = (int*)(od + OD_CC);     // counts, then cursors
    int*   bsum   = (int*)(od + OD_BSUM);
    float* ss     = od + OD_SS;
    double* sums  = (double*)(od + OD_SUMS);

    const int* src  = ei;
    const int* dst  = ei + NE;
    const int* esrc = eio;
    const int* edst = eio + NEO;

    // ---- one-time CSR build (amortized over 6 layers) ----
    hipMemsetAsync(cc, 0, NN * sizeof(int), stream);
    k_hist<<<(NE + 255) / 256, 256, 0, stream>>>(dst, cc);
    k_scanA<<<SCAN_NB, SCAN_BS, 0, stream>>>(cc, rowptr, bsum, dinv);
    k_scanB<<<1, 256, 0, stream>>>(bsum);
    k_scanC<<<SCAN_NB, SCAN_BS, 0, stream>>>(rowptr, bsum, cc);
    k_build<<<(NE + 255) / 256, 256, 0, stream>>>(src, dst, cc, ecol);

    k_embed<<<(NN + 63) / 64, 256, 0, stream>>>(x, W_emb, b_emb, xe);

    for (int l = 0; l < NL; l++) {
        k_hw<<<(NN + 63) / 64, 256, 0, stream>>>(xe, conv_W + l * 64 * 64, dinv, hws, sums);
        k_spmm<<<SPMM_BLOCKS, 256, 0, stream>>>(rowptr, ecol, hws, dinv, agg, sums);
        k_finalize<<<1, 64, 0, stream>>>(sums, bn_g + l * 64, bn_b + l * 64, ss);
        k_apply<<<(NN * HID) / 256, 256, 0, stream>>>(agg, ss, xe);
    }

    k_out<<<(NEO + 255) / 256, 256, 0, stream>>>(esrc, edst, xe, fc_W, fc_b, out);
}

// Round 3
// 930.437 us; speedup vs baseline: 3.1803x; 1.2040x over previous
//
#include <hip/hip_runtime.h>

#define NN 100000
#define NE 1600000
#define NEO 400000
#define HID 64
#define NL 6
#define BN_EPS 1e-5f

#define SPMM_BLOCKS 2048
#define SCAN_BS 512
#define SCAN_NB 196   // ceil(100000/512)

// ---- d_ws layout (float offsets): 70.4MB ----
#define OFF_ECOL 0                        // NE ints
#define OFF_XE   NE                       // NN*64 f
#define OFF_AGG  (OFF_XE + NN * HID)      // NN*64 f
#define OFF_HWB  (OFF_AGG + NN * HID)     // NN*64 bf16 = NN*32 f

// ---- d_out head used as scratch (dead before k_out overwrites) ----
#define OD_DINV   0                      // NN f
#define OD_ROWPTR 100000                 // NN+1 ints (rounded 100352)
#define OD_CC     200352                 // NN ints (counts, then cursors)
#define OD_BSUM   300352                 // 256 ints
#define OD_SS     300608                 // 128 f (scale/shift)
#define OD_SUMS   300736                 // 16*128 doubles

static __device__ __forceinline__ unsigned short f2bf(float f) {
    unsigned u = __float_as_uint(f);
    unsigned r = (u + 0x7FFF + ((u >> 16) & 1)) >> 16;  // RNE
    return (unsigned short)r;
}
static __device__ __forceinline__ float bf2f(unsigned short h) {
    return __uint_as_float((unsigned)h << 16);
}

__global__ void k_hist(const int* __restrict__ dst, int* __restrict__ cnt) {
    int e = blockIdx.x * blockDim.x + threadIdx.x;
    if (e < NE) atomicAdd(&cnt[dst[e]], 1);
}

__global__ void k_scanA(const int* __restrict__ cnt, int* __restrict__ rowptr,
                        int* __restrict__ bsum, float* __restrict__ dinv) {
    __shared__ int sh[SCAN_BS];
    int t = threadIdx.x;
    int i = blockIdx.x * SCAN_BS + t;
    int v = (i < NN) ? cnt[i] : 0;
    sh[t] = v;
    __syncthreads();
    for (int off = 1; off < SCAN_BS; off <<= 1) {
        int a = (t >= off) ? sh[t - off] : 0;
        __syncthreads();
        sh[t] += a;
        __syncthreads();
    }
    if (i < NN) {
        rowptr[i] = sh[t] - v;
        dinv[i] = rsqrtf((float)(v + 1));   // deg = in-deg + self-loop
    }
    if (t == SCAN_BS - 1) bsum[blockIdx.x] = sh[t];
}

__global__ void k_scanB(int* __restrict__ bsum) {
    __shared__ int sh[256];
    int t = threadIdx.x;
    int v = (t < SCAN_NB) ? bsum[t] : 0;
    sh[t] = v;
    __syncthreads();
    for (int off = 1; off < 256; off <<= 1) {
        int a = (t >= off) ? sh[t - off] : 0;
        __syncthreads();
        sh[t] += a;
        __syncthreads();
    }
    if (t < SCAN_NB) bsum[t] = (t == 0) ? 0 : sh[t - 1];
}

__global__ void k_scanC(int* __restrict__ rowptr, const int* __restrict__ bsum,
                        int* __restrict__ cursor) {
    int i = blockIdx.x * SCAN_BS + threadIdx.x;
    if (i < NN) {
        int rp = rowptr[i] + bsum[blockIdx.x];
        rowptr[i] = rp;
        cursor[i] = rp;
    }
    if (i == 0) rowptr[NN] = NE;
}

__global__ void k_build(const int* __restrict__ src, const int* __restrict__ dst,
                        int* __restrict__ cursor, int* __restrict__ ecol) {
    int e = blockIdx.x * blockDim.x + threadIdx.x;
    if (e < NE) {
        int pos = atomicAdd(&cursor[dst[e]], 1);
        ecol[pos] = src[e];
    }
}

// xe = x[NN,16] @ W[16,64] + b
__global__ void k_embed(const float* __restrict__ x, const float* __restrict__ W,
                        const float* __restrict__ b, float* __restrict__ xe) {
    __shared__ float Ws[16 * 64];
    __shared__ float bs[64];
    int t = threadIdx.x;
    for (int i = t; i < 16 * 64; i += 256) Ws[i] = W[i];
    if (t < 64) bs[t] = b[t];
    __syncthreads();
    int c = t & 63, r = t >> 6;
    int n0 = blockIdx.x * 64;
    for (int n = n0 + r; n < n0 + 64 && n < NN; n += 4) {
        const float* xr = x + n * 16;
        float acc = bs[c];
#pragma unroll
        for (int k = 0; k < 16; k++) acc = fmaf(xr[k], Ws[k * 64 + c], acc);
        xe[n * 64 + c] = acc;
    }
}

// fused: xe += relu(agg*sc+sh) (prev layer's BN, if apply); hwb = bf16(dinv*(xe@W))
__global__ void k_hw(const float* __restrict__ xeIn, float* __restrict__ xe,
                     const float* __restrict__ W, const float* __restrict__ dinv,
                     const float* __restrict__ agg, const float* __restrict__ ss,
                     unsigned short* __restrict__ hwb, double* __restrict__ sums,
                     int apply) {
    __shared__ float Ws[64 * 64];
    __shared__ float Xs[4 * 64];
    int t = threadIdx.x;
    if (blockIdx.x == 0) {
        for (int i = t; i < 16 * 128; i += 256) sums[i] = 0.0;
    }
    for (int i = t; i < 64 * 64; i += 256) Ws[i] = W[i];
    int c = t & 63, r = t >> 6;
    int n0 = blockIdx.x * 64;
    __syncthreads();
    for (int i = 0; i < 16; i++) {
        int n = n0 + i * 4 + r;
        if (i) __syncthreads();
        if (n < NN) {
            float xv = xeIn[n * 64 + c];
            if (apply) {
                float v = fmaf(agg[n * 64 + c], ss[c], ss[64 + c]);
                xv += fmaxf(v, 0.f);
                xe[n * 64 + c] = xv;
            }
            Xs[t] = xv;
        }
        __syncthreads();
        if (n < NN) {
            float acc = 0.f;
#pragma unroll
            for (int k = 0; k < 64; k++)
                acc = fmaf(Xs[r * 64 + k], Ws[k * 64 + c], acc);
            hwb[n * 64 + c] = f2bf(acc * dinv[n]);
        }
    }
}

// agg[d] = dinv[d]*(hwb[d] + sum_{s in N(d)} hwb[s]); fused BN stats
__global__ void k_spmm(const int* __restrict__ rowptr, const int* __restrict__ ecol,
                       const unsigned short* __restrict__ hwb, const float* __restrict__ dinv,
                       float* __restrict__ agg, double* __restrict__ sums) {
    int t = threadIdx.x, c = t & 63, r = t >> 6;
    double ls = 0.0, lq = 0.0;
    for (int row = blockIdx.x * 4 + r; row < NN; row += SPMM_BLOCKS * 4) {
        int p0 = __builtin_amdgcn_readfirstlane(rowptr[row]);
        int p1 = __builtin_amdgcn_readfirstlane(rowptr[row + 1]);
        float acc = bf2f(hwb[row * 64 + c]);
        int p = p0;
        for (; p + 8 <= p1; p += 8) {
            int s0 = ecol[p],     s1 = ecol[p + 1], s2 = ecol[p + 2], s3 = ecol[p + 3];
            int s4 = ecol[p + 4], s5 = ecol[p + 5], s6 = ecol[p + 6], s7 = ecol[p + 7];
            float v0 = bf2f(hwb[s0 * 64 + c]);
            float v1 = bf2f(hwb[s1 * 64 + c]);
            float v2 = bf2f(hwb[s2 * 64 + c]);
            float v3 = bf2f(hwb[s3 * 64 + c]);
            float v4 = bf2f(hwb[s4 * 64 + c]);
            float v5 = bf2f(hwb[s5 * 64 + c]);
            float v6 = bf2f(hwb[s6 * 64 + c]);
            float v7 = bf2f(hwb[s7 * 64 + c]);
            acc += ((v0 + v1) + (v2 + v3)) + ((v4 + v5) + (v6 + v7));
        }
        for (; p < p1; p++) acc += bf2f(hwb[ecol[p] * 64 + c]);
        float v = acc * dinv[row];
        agg[row * 64 + c] = v;
        ls += v;
        lq += (double)v * v;
    }
    __shared__ double Ss[256], Sq[256];
    Ss[t] = ls; Sq[t] = lq;
    __syncthreads();
    if (r == 0) {
        double a = Ss[c] + Ss[64 + c] + Ss[128 + c] + Ss[192 + c];
        double b = Sq[c] + Sq[64 + c] + Sq[128 + c] + Sq[192 + c];
        double* sh = sums + (blockIdx.x & 15) * 128;
        atomicAdd(&sh[c], a);
        atomicAdd(&sh[64 + c], b);
    }
}

__global__ void k_finalize(const double* __restrict__ sums, const float* __restrict__ gamma,
                           const float* __restrict__ beta, float* __restrict__ ss) {
    int c = threadIdx.x;  // 64 threads
    double s = 0.0, q = 0.0;
#pragma unroll
    for (int k = 0; k < 16; k++) { s += sums[k * 128 + c]; q += sums[k * 128 + 64 + c]; }
    double mean = s / (double)NN;
    double var = q / (double)NN - mean * mean;
    float sc = gamma[c] * rsqrtf((float)var + BN_EPS);
    ss[c] = sc;
    ss[64 + c] = beta[c] - (float)mean * sc;
}

// final layer: xe += relu(agg*scale + shift)
__global__ void k_apply(const float* __restrict__ agg, const float* __restrict__ ss,
                        float* __restrict__ xe) {
    int i = blockIdx.x * blockDim.x + threadIdx.x;
    if (i < NN * HID) {
        int c = i & 63;
        float v = fmaf(agg[i], ss[c], ss[64 + c]);
        xe[i] += fmaxf(v, 0.f);
    }
}

// out[e] = [xe[s]; xe[d]] @ fc_W + fc_b
__global__ void k_out(const int* __restrict__ esrc, const int* __restrict__ edst,
                      const float* __restrict__ xe, const float* __restrict__ fcW,
                      const float* __restrict__ fcb, float* __restrict__ out) {
    __shared__ float Ws[256];
    __shared__ float bs[2];
    int t = threadIdx.x;
    for (int i = t; i < 256; i += 256) Ws[i] = fcW[i];
    if (t < 2) bs[t] = fcb[t];
    __syncthreads();
    int e = blockIdx.x * blockDim.x + t;
    if (e < NEO) {
        int s = esrc[e], d = edst[e];
        const float4* rs = (const float4*)(xe + s * 64);
        const float4* rd = (const float4*)(xe + d * 64);
        float a0 = bs[0], a1 = bs[1];
#pragma unroll
        for (int i = 0; i < 16; i++) {
            float4 v = rs[i];
            a0 += v.x * Ws[(i * 4 + 0) * 2] + v.y * Ws[(i * 4 + 1) * 2] +
                  v.z * Ws[(i * 4 + 2) * 2] + v.w * Ws[(i * 4 + 3) * 2];
            a1 += v.x * Ws[(i * 4 + 0) * 2 + 1] + v.y * Ws[(i * 4 + 1) * 2 + 1] +
                  v.z * Ws[(i * 4 + 2) * 2 + 1] + v.w * Ws[(i * 4 + 3) * 2 + 1];
        }
#pragma unroll
        for (int i = 0; i < 16; i++) {
            float4 v = rd[i];
            a0 += v.x * Ws[(64 + i * 4 + 0) * 2] + v.y * Ws[(64 + i * 4 + 1) * 2] +
                  v.z * Ws[(64 + i * 4 + 2) * 2] + v.w * Ws[(64 + i * 4 + 3) * 2];
            a1 += v.x * Ws[(64 + i * 4 + 0) * 2 + 1] + v.y * Ws[(64 + i * 4 + 1) * 2 + 1] +
                  v.z * Ws[(64 + i * 4 + 2) * 2 + 1] + v.w * Ws[(64 + i * 4 + 3) * 2 + 1];
        }
        out[e * 2] = a0;
        out[e * 2 + 1] = a1;
    }
}

extern "C" void kernel_launch(void* const* d_in, const int* in_sizes, int n_in,
                              void* d_out, int out_size, void* d_ws, size_t ws_size,
                              hipStream_t stream) {
    const float* x      = (const float*)d_in[0];
    const int*   ei     = (const int*)d_in[1];
    const int*   eio    = (const int*)d_in[2];
    const float* W_emb  = (const float*)d_in[3];
    const float* b_emb  = (const float*)d_in[4];
    const float* conv_W = (const float*)d_in[5];
    // d_in[6] conv_b: cancels inside BN
    const float* bn_g   = (const float*)d_in[7];
    const float* bn_b   = (const float*)d_in[8];
    const float* fc_W   = (const float*)d_in[9];
    const float* fc_b   = (const float*)d_in[10];
    float* out = (float*)d_out;

    float* ws   = (float*)d_ws;
    int*   ecol = (int*)(ws + OFF_ECOL);
    float* xe   = ws + OFF_XE;
    float* agg  = ws + OFF_AGG;
    unsigned short* hwb = (unsigned short*)(ws + OFF_HWB);

    float* od     = (float*)d_out;
    float* dinv   = od + OD_DINV;
    int*   rowptr = (int*)(od + OD_ROWPTR);
    int*   cc     = (int*)(od + OD_CC);
    int*   bsum   = (int*)(od + OD_BSUM);
    float* ss     = od + OD_SS;
    double* sums  = (double*)(od + OD_SUMS);

    const int* src  = ei;
    const int* dst  = ei + NE;
    const int* esrc = eio;
    const int* edst = eio + NEO;

    // ---- one-time CSR build ----
    hipMemsetAsync(cc, 0, NN * sizeof(int), stream);
    k_hist<<<(NE + 255) / 256, 256, 0, stream>>>(dst, cc);
    k_scanA<<<SCAN_NB, SCAN_BS, 0, stream>>>(cc, rowptr, bsum, dinv);
    k_scanB<<<1, 256, 0, stream>>>(bsum);
    k_scanC<<<SCAN_NB, SCAN_BS, 0, stream>>>(rowptr, bsum, cc);
    k_build<<<(NE + 255) / 256, 256, 0, stream>>>(src, dst, cc, ecol);

    k_embed<<<(NN + 63) / 64, 256, 0, stream>>>(x, W_emb, b_emb, xe);

    for (int l = 0; l < NL; l++) {
        k_hw<<<(NN + 63) / 64, 256, 0, stream>>>(xe, xe, conv_W + l * 64 * 64, dinv,
                                                 agg, ss, hwb, sums, l > 0 ? 1 : 0);
        k_spmm<<<SPMM_BLOCKS, 256, 0, stream>>>(rowptr, ecol, hwb, dinv, agg, sums);
        k_finalize<<<1, 64, 0, stream>>>(sums, bn_g + l * 64, bn_b + l * 64, ss);
    }
    k_apply<<<(NN * HID) / 256, 256, 0, stream>>>(agg, ss, xe);

    k_out<<<(NEO + 255) / 256, 256, 0, stream>>>(esrc, edst, xe, fc_W, fc_b, out);
}

// Round 4
// 785.146 us; speedup vs baseline: 3.7688x; 1.1850x over previous
//
#include <hip/hip_runtime.h>

#define NN 100000
#define NE 1600000
#define NEO 400000
#define HID 64
#define NL 6
#define BN_EPS 1e-5f

#define SPMM_BLOCKS 2048
#define SCAN_BS 512
#define SCAN_NB 196   // ceil(100000/512)

// ---- d_ws layout (float offsets): 70.4MB ----
#define OFF_ECOL 0                        // NE ints
#define OFF_XE   NE                       // NN*64 f
#define OFF_AGG  (OFF_XE + NN * HID)      // NN*64 f
#define OFF_HWB  (OFF_AGG + NN * HID)     // NN*64 bf16 = NN*32 f

// ---- d_out head used as scratch (dead before k_out overwrites) ----
#define OD_DINV   0                      // NN f
#define OD_ROWPTR 100000                 // NN+1 ints (rounded 100352)
#define OD_CC     200352                 // NN ints (counts, then cursors)
#define OD_BSUM   300352                 // 256 ints
#define OD_SS     300608                 // 128 f (scale/shift)
#define OD_SUMS   300736                 // 16*128 doubles

static __device__ __forceinline__ unsigned short f2bf(float f) {
    unsigned u = __float_as_uint(f);
    unsigned r = (u + 0x7FFF + ((u >> 16) & 1)) >> 16;  // RNE
    return (unsigned short)r;
}
static __device__ __forceinline__ float bflo(unsigned u) {   // low bf16 of a uint
    return __uint_as_float(u << 16);
}
static __device__ __forceinline__ float bfhi(unsigned u) {   // high bf16 of a uint
    return __uint_as_float(u & 0xFFFF0000u);
}

__global__ void k_hist(const int* __restrict__ dst, int* __restrict__ cnt) {
    int e = blockIdx.x * blockDim.x + threadIdx.x;
    if (e < NE) atomicAdd(&cnt[dst[e]], 1);
}

__global__ void k_scanA(const int* __restrict__ cnt, int* __restrict__ rowptr,
                        int* __restrict__ bsum, float* __restrict__ dinv) {
    __shared__ int sh[SCAN_BS];
    int t = threadIdx.x;
    int i = blockIdx.x * SCAN_BS + t;
    int v = (i < NN) ? cnt[i] : 0;
    sh[t] = v;
    __syncthreads();
    for (int off = 1; off < SCAN_BS; off <<= 1) {
        int a = (t >= off) ? sh[t - off] : 0;
        __syncthreads();
        sh[t] += a;
        __syncthreads();
    }
    if (i < NN) {
        rowptr[i] = sh[t] - v;
        dinv[i] = rsqrtf((float)(v + 1));   // deg = in-deg + self-loop
    }
    if (t == SCAN_BS - 1) bsum[blockIdx.x] = sh[t];
}

__global__ void k_scanB(int* __restrict__ bsum) {
    __shared__ int sh[256];
    int t = threadIdx.x;
    int v = (t < SCAN_NB) ? bsum[t] : 0;
    sh[t] = v;
    __syncthreads();
    for (int off = 1; off < 256; off <<= 1) {
        int a = (t >= off) ? sh[t - off] : 0;
        __syncthreads();
        sh[t] += a;
        __syncthreads();
    }
    if (t < SCAN_NB) bsum[t] = (t == 0) ? 0 : sh[t - 1];
}

__global__ void k_scanC(int* __restrict__ rowptr, const int* __restrict__ bsum,
                        int* __restrict__ cursor) {
    int i = blockIdx.x * SCAN_BS + threadIdx.x;
    if (i < NN) {
        int rp = rowptr[i] + bsum[blockIdx.x];
        rowptr[i] = rp;
        cursor[i] = rp;
    }
    if (i == 0) rowptr[NN] = NE;
}

__global__ void k_build(const int* __restrict__ src, const int* __restrict__ dst,
                        int* __restrict__ cursor, int* __restrict__ ecol) {
    int e = blockIdx.x * blockDim.x + threadIdx.x;
    if (e < NE) {
        int pos = atomicAdd(&cursor[dst[e]], 1);
        ecol[pos] = src[e];
    }
}

// xe = x[NN,16] @ W[16,64] + b
__global__ void k_embed(const float* __restrict__ x, const float* __restrict__ W,
                        const float* __restrict__ b, float* __restrict__ xe) {
    __shared__ float Ws[16 * 64];
    __shared__ float bs[64];
    int t = threadIdx.x;
    for (int i = t; i < 16 * 64; i += 256) Ws[i] = W[i];
    if (t < 64) bs[t] = b[t];
    __syncthreads();
    int c = t & 63, r = t >> 6;
    int n0 = blockIdx.x * 64;
    for (int n = n0 + r; n < n0 + 64 && n < NN; n += 4) {
        const float* xr = x + n * 16;
        float acc = bs[c];
#pragma unroll
        for (int k = 0; k < 16; k++) acc = fmaf(xr[k], Ws[k * 64 + c], acc);
        xe[n * 64 + c] = acc;
    }
}

// fused: xe += relu(agg*sc+sh) (prev BN, if apply); hwb = bf16(dinv*(xe@W))
// 4x4 register-blocked: thread (i=t>>4, j=t&15) -> rows 4i..4i+3, cols 4j..4j+3
__global__ void k_hw(const float* __restrict__ xeIn, float* __restrict__ xe,
                     const float* __restrict__ W, const float* __restrict__ dinv,
                     const float* __restrict__ agg, const float* __restrict__ ss,
                     unsigned short* __restrict__ hwb, double* __restrict__ sums,
                     int apply) {
    __shared__ float Ws[64 * 64];     // Ws[k][c]
    __shared__ float Xs[64 * 65];     // Xs[n][k], +1 pad: bank-spread reads
    int t = threadIdx.x;
    if (blockIdx.x == 0) {
        for (int i = t; i < 16 * 128; i += 256) sums[i] = 0.0;
    }
#pragma unroll
    for (int i = 0; i < 4; i++)
        ((float4*)Ws)[t + i * 256] = ((const float4*)W)[t + i * 256];
    int c = t & 63, rr = t >> 6;
    int n0 = blockIdx.x * 64;
#pragma unroll
    for (int i = 0; i < 16; i++) {
        int rl = i * 4 + rr;
        int n = n0 + rl;
        float xv = 0.f;
        if (n < NN) {
            xv = xeIn[n * 64 + c];
            if (apply) {
                float v = fmaf(agg[n * 64 + c], ss[c], ss[64 + c]);
                xv += fmaxf(v, 0.f);
                xe[n * 64 + c] = xv;
            }
        }
        Xs[rl * 65 + c] = xv;
    }
    __syncthreads();

    int r0 = (t >> 4) * 4, c0 = (t & 15) * 4;
    float acc[4][4];
#pragma unroll
    for (int a = 0; a < 4; a++)
#pragma unroll
        for (int b = 0; b < 4; b++) acc[a][b] = 0.f;
    for (int k = 0; k < 64; k++) {
        float4 wv = *(const float4*)&Ws[k * 64 + c0];
        float x0 = Xs[(r0 + 0) * 65 + k];
        float x1 = Xs[(r0 + 1) * 65 + k];
        float x2 = Xs[(r0 + 2) * 65 + k];
        float x3 = Xs[(r0 + 3) * 65 + k];
        acc[0][0] = fmaf(x0, wv.x, acc[0][0]); acc[0][1] = fmaf(x0, wv.y, acc[0][1]);
        acc[0][2] = fmaf(x0, wv.z, acc[0][2]); acc[0][3] = fmaf(x0, wv.w, acc[0][3]);
        acc[1][0] = fmaf(x1, wv.x, acc[1][0]); acc[1][1] = fmaf(x1, wv.y, acc[1][1]);
        acc[1][2] = fmaf(x1, wv.z, acc[1][2]); acc[1][3] = fmaf(x1, wv.w, acc[1][3]);
        acc[2][0] = fmaf(x2, wv.x, acc[2][0]); acc[2][1] = fmaf(x2, wv.y, acc[2][1]);
        acc[2][2] = fmaf(x2, wv.z, acc[2][2]); acc[2][3] = fmaf(x2, wv.w, acc[2][3]);
        acc[3][0] = fmaf(x3, wv.x, acc[3][0]); acc[3][1] = fmaf(x3, wv.y, acc[3][1]);
        acc[3][2] = fmaf(x3, wv.z, acc[3][2]); acc[3][3] = fmaf(x3, wv.w, acc[3][3]);
    }
#pragma unroll
    for (int a = 0; a < 4; a++) {
        int n = n0 + r0 + a;
        if (n < NN) {
            float di = dinv[n];
            unsigned lo = ((unsigned)f2bf(acc[a][1]) << 16) | f2bf(acc[a][0] * di) ;
            // note: recompute carefully below (scale all four)
            float v0 = acc[a][0] * di, v1 = acc[a][1] * di;
            float v2 = acc[a][2] * di, v3 = acc[a][3] * di;
            uint2 pk;
            pk.x = ((unsigned)f2bf(v1) << 16) | f2bf(v0);
            pk.y = ((unsigned)f2bf(v3) << 16) | f2bf(v2);
            *(uint2*)(hwb + n * 64 + c0) = pk;
            (void)lo;
        }
    }
}

// agg[d] = dinv[d]*(hwb[d] + sum_{s in N(d)} hwb[s]); fused BN stats.
// Wave = 1 row; 4 groups of 16 lanes stride the edge list; lane q owns ch 4q..4q+3.
__global__ void k_spmm(const int* __restrict__ rowptr, const int* __restrict__ ecol,
                       const unsigned short* __restrict__ hwb, const float* __restrict__ dinv,
                       float* __restrict__ agg, double* __restrict__ sums) {
    int t = threadIdx.x;
    int w = t >> 6, l = t & 63;
    int grp = l >> 4, q = l & 15;
    const uint2* hw2 = (const uint2*)hwb;   // row s at hw2 + s*16, lane q reads +q
    float ls0 = 0.f, ls1 = 0.f, ls2 = 0.f, ls3 = 0.f;
    float lq0 = 0.f, lq1 = 0.f, lq2 = 0.f, lq3 = 0.f;
    for (int row = blockIdx.x * 4 + w; row < NN; row += SPMM_BLOCKS * 4) {
        int p0 = __builtin_amdgcn_readfirstlane(rowptr[row]);
        int p1 = __builtin_amdgcn_readfirstlane(rowptr[row + 1]);
        uint2 sv = hw2[row * 16 + q];       // self row (same addr across grps)
        float a0 = 0.f, a1 = 0.f, a2 = 0.f, a3 = 0.f;
        int p = p0 + grp;
        for (; p + 4 < p1; p += 8) {        // unroll 2: both loads in flight
            int s0 = ecol[p], s1 = ecol[p + 4];
            uint2 u0 = hw2[s0 * 16 + q];
            uint2 u1 = hw2[s1 * 16 + q];
            a0 += bflo(u0.x); a1 += bfhi(u0.x); a2 += bflo(u0.y); a3 += bfhi(u0.y);
            a0 += bflo(u1.x); a1 += bfhi(u1.x); a2 += bflo(u1.y); a3 += bfhi(u1.y);
        }
        if (p < p1) {
            int s0 = ecol[p];
            uint2 u0 = hw2[s0 * 16 + q];
            a0 += bflo(u0.x); a1 += bfhi(u0.x); a2 += bflo(u0.y); a3 += bfhi(u0.y);
        }
        // reduce across the 4 groups (lane bits 4,5)
        a0 += __shfl_xor(a0, 16, 64); a0 += __shfl_xor(a0, 32, 64);
        a1 += __shfl_xor(a1, 16, 64); a1 += __shfl_xor(a1, 32, 64);
        a2 += __shfl_xor(a2, 16, 64); a2 += __shfl_xor(a2, 32, 64);
        a3 += __shfl_xor(a3, 16, 64); a3 += __shfl_xor(a3, 32, 64);
        float di = dinv[row];
        float v0 = (a0 + bflo(sv.x)) * di;
        float v1 = (a1 + bfhi(sv.x)) * di;
        float v2 = (a2 + bflo(sv.y)) * di;
        float v3 = (a3 + bfhi(sv.y)) * di;
        if (grp == 0) {
            float4 o = make_float4(v0, v1, v2, v3);
            *(float4*)(agg + row * 64 + 4 * q) = o;   // 16 lanes x 16B = 256B
        }
        ls0 += v0; ls1 += v1; ls2 += v2; ls3 += v3;
        lq0 = fmaf(v0, v0, lq0); lq1 = fmaf(v1, v1, lq1);
        lq2 = fmaf(v2, v2, lq2); lq3 = fmaf(v3, v3, lq3);
    }
    __shared__ float Ss[4][64], Sq[4][64];
    if (grp == 0) {
        Ss[w][4 * q + 0] = ls0; Ss[w][4 * q + 1] = ls1;
        Ss[w][4 * q + 2] = ls2; Ss[w][4 * q + 3] = ls3;
        Sq[w][4 * q + 0] = lq0; Sq[w][4 * q + 1] = lq1;
        Sq[w][4 * q + 2] = lq2; Sq[w][4 * q + 3] = lq3;
    }
    __syncthreads();
    if (t < 64) {
        float a = Ss[0][t] + Ss[1][t] + Ss[2][t] + Ss[3][t];
        float b = Sq[0][t] + Sq[1][t] + Sq[2][t] + Sq[3][t];
        double* sh = sums + (blockIdx.x & 15) * 128;
        atomicAdd(&sh[t], (double)a);
        atomicAdd(&sh[64 + t], (double)b);
    }
}

__global__ void k_finalize(const double* __restrict__ sums, const float* __restrict__ gamma,
                           const float* __restrict__ beta, float* __restrict__ ss) {
    int c = threadIdx.x;  // 64 threads
    double s = 0.0, q = 0.0;
#pragma unroll
    for (int k = 0; k < 16; k++) { s += sums[k * 128 + c]; q += sums[k * 128 + 64 + c]; }
    double mean = s / (double)NN;
    double var = q / (double)NN - mean * mean;
    float sc = gamma[c] * rsqrtf((float)var + BN_EPS);
    ss[c] = sc;
    ss[64 + c] = beta[c] - (float)mean * sc;
}

// final layer: xe += relu(agg*scale + shift)
__global__ void k_apply(const float* __restrict__ agg, const float* __restrict__ ss,
                        float* __restrict__ xe) {
    int i = blockIdx.x * blockDim.x + threadIdx.x;
    if (i < NN * HID) {
        int c = i & 63;
        float v = fmaf(agg[i], ss[c], ss[64 + c]);
        xe[i] += fmaxf(v, 0.f);
    }
}

// out[e] = [xe[s]; xe[d]] @ fc_W + fc_b
__global__ void k_out(const int* __restrict__ esrc, const int* __restrict__ edst,
                      const float* __restrict__ xe, const float* __restrict__ fcW,
                      const float* __restrict__ fcb, float* __restrict__ out) {
    __shared__ float Ws[256];
    __shared__ float bs[2];
    int t = threadIdx.x;
    for (int i = t; i < 256; i += 256) Ws[i] = fcW[i];
    if (t < 2) bs[t] = fcb[t];
    __syncthreads();
    int e = blockIdx.x * blockDim.x + t;
    if (e < NEO) {
        int s = esrc[e], d = edst[e];
        const float4* rs = (const float4*)(xe + s * 64);
        const float4* rd = (const float4*)(xe + d * 64);
        float a0 = bs[0], a1 = bs[1];
#pragma unroll
        for (int i = 0; i < 16; i++) {
            float4 v = rs[i];
            a0 += v.x * Ws[(i * 4 + 0) * 2] + v.y * Ws[(i * 4 + 1) * 2] +
                  v.z * Ws[(i * 4 + 2) * 2] + v.w * Ws[(i * 4 + 3) * 2];
            a1 += v.x * Ws[(i * 4 + 0) * 2 + 1] + v.y * Ws[(i * 4 + 1) * 2 + 1] +
                  v.z * Ws[(i * 4 + 2) * 2 + 1] + v.w * Ws[(i * 4 + 3) * 2 + 1];
        }
#pragma unroll
        for (int i = 0; i < 16; i++) {
            float4 v = rd[i];
            a0 += v.x * Ws[(64 + i * 4 + 0) * 2] + v.y * Ws[(64 + i * 4 + 1) * 2] +
                  v.z * Ws[(64 + i * 4 + 2) * 2] + v.w * Ws[(64 + i * 4 + 3) * 2];
            a1 += v.x * Ws[(64 + i * 4 + 0) * 2 + 1] + v.y * Ws[(64 + i * 4 + 1) * 2 + 1] +
                  v.z * Ws[(64 + i * 4 + 2) * 2 + 1] + v.w * Ws[(64 + i * 4 + 3) * 2 + 1];
        }
        out[e * 2] = a0;
        out[e * 2 + 1] = a1;
    }
}

extern "C" void kernel_launch(void* const* d_in, const int* in_sizes, int n_in,
                              void* d_out, int out_size, void* d_ws, size_t ws_size,
                              hipStream_t stream) {
    const float* x      = (const float*)d_in[0];
    const int*   ei     = (const int*)d_in[1];
    const int*   eio    = (const int*)d_in[2];
    const float* W_emb  = (const float*)d_in[3];
    const float* b_emb  = (const float*)d_in[4];
    const float* conv_W = (const float*)d_in[5];
    // d_in[6] conv_b: cancels inside BN
    const float* bn_g   = (const float*)d_in[7];
    const float* bn_b   = (const float*)d_in[8];
    const float* fc_W   = (const float*)d_in[9];
    const float* fc_b   = (const float*)d_in[10];
    float* out = (float*)d_out;

    float* ws   = (float*)d_ws;
    int*   ecol = (int*)(ws + OFF_ECOL);
    float* xe   = ws + OFF_XE;
    float* agg  = ws + OFF_AGG;
    unsigned short* hwb = (unsigned short*)(ws + OFF_HWB);

    float* od     = (float*)d_out;
    float* dinv   = od + OD_DINV;
    int*   rowptr = (int*)(od + OD_ROWPTR);
    int*   cc     = (int*)(od + OD_CC);
    int*   bsum   = (int*)(od + OD_BSUM);
    float* ss     = od + OD_SS;
    double* sums  = (double*)(od + OD_SUMS);

    const int* src  = ei;
    const int* dst  = ei + NE;
    const int* esrc = eio;
    const int* edst = eio + NEO;

    // ---- one-time CSR build ----
    hipMemsetAsync(cc, 0, NN * sizeof(int), stream);
    k_hist<<<(NE + 255) / 256, 256, 0, stream>>>(dst, cc);
    k_scanA<<<SCAN_NB, SCAN_BS, 0, stream>>>(cc, rowptr, bsum, dinv);
    k_scanB<<<1, 256, 0, stream>>>(bsum);
    k_scanC<<<SCAN_NB, SCAN_BS, 0, stream>>>(rowptr, bsum, cc);
    k_build<<<(NE + 255) / 256, 256, 0, stream>>>(src, dst, cc, ecol);

    k_embed<<<(NN + 63) / 64, 256, 0, stream>>>(x, W_emb, b_emb, xe);

    for (int l = 0; l < NL; l++) {
        k_hw<<<(NN + 63) / 64, 256, 0, stream>>>(xe, xe, conv_W + l * 64 * 64, dinv,
                                                 agg, ss, hwb, sums, l > 0 ? 1 : 0);
        k_spmm<<<SPMM_BLOCKS, 256, 0, stream>>>(rowptr, ecol, hwb, dinv, agg, sums);
        k_finalize<<<1, 64, 0, stream>>>(sums, bn_g + l * 64, bn_b + l * 64, ss);
    }
    k_apply<<<(NN * HID) / 256, 256, 0, stream>>>(agg, ss, xe);

    k_out<<<(NEO + 255) / 256, 256, 0, stream>>>(esrc, edst, xe, fc_W, fc_b, out);
}

// Round 5
// 750.361 us; speedup vs baseline: 3.9436x; 1.0464x over previous
//
#include <hip/hip_runtime.h>

#define NN 100000
#define NE 1600000
#define NEO 400000
#define HID 64
#define NL 6
#define BN_EPS 1e-5f

#define SPMM_BLOCKS 2048
#define SCAN_BS 512
#define SCAN_NB 196   // ceil(100000/512)
#define GRP_ROWS 12500          // NN/8 rows per XCD group
#define BUILD_BPG 784           // blocks per group for hist/build

// ---- d_ws layout (float offsets): 70.4MB ----
#define OFF_ECOL 0                        // NE ints
#define OFF_XE   NE                       // NN*64 f
#define OFF_AGG  (OFF_XE + NN * HID)      // NN*64 f
#define OFF_HWB  (OFF_AGG + NN * HID)     // NN*64 bf16 = NN*32 f

// ---- d_out head used as scratch (dead before k_out overwrites) ----
#define OD_DINV   0                      // NN f
#define OD_ROWPTR 100000                 // NN+1 ints (rounded 100352)
#define OD_CC     200352                 // NN ints (counts, then cursors)
#define OD_BSUM   300352                 // 256 ints
#define OD_SS     300608                 // 128 f (scale/shift)
#define OD_SUMS   300736                 // 16*128 doubles

static __device__ __forceinline__ unsigned short f2bf(float f) {
    unsigned u = __float_as_uint(f);
    unsigned r = (u + 0x7FFF + ((u >> 16) & 1)) >> 16;  // RNE
    return (unsigned short)r;
}
static __device__ __forceinline__ float bflo(unsigned u) {
    return __uint_as_float(u << 16);
}
static __device__ __forceinline__ float bfhi(unsigned u) {
    return __uint_as_float(u & 0xFFFF0000u);
}

// XCD-partitioned histogram: group g (blockIdx&7) owns dst range [g*GRP_ROWS, ...)
// -> each cnt line is touched by one XCD's L2 only (no cross-L2 partial-line churn)
__global__ void k_hist(const int* __restrict__ dst, int* __restrict__ cnt) {
    int g = blockIdx.x & 7;
    int b = blockIdx.x >> 3;
    int lo = g * GRP_ROWS, hi = lo + GRP_ROWS;
    for (int e = b * blockDim.x + threadIdx.x; e < NE; e += BUILD_BPG * blockDim.x) {
        int d = dst[e];
        if (d >= lo && d < hi) atomicAdd(&cnt[d], 1);
    }
}

__global__ void k_scanA(const int* __restrict__ cnt, int* __restrict__ rowptr,
                        int* __restrict__ bsum, float* __restrict__ dinv) {
    __shared__ int sh[SCAN_BS];
    int t = threadIdx.x;
    int i = blockIdx.x * SCAN_BS + t;
    int v = (i < NN) ? cnt[i] : 0;
    sh[t] = v;
    __syncthreads();
    for (int off = 1; off < SCAN_BS; off <<= 1) {
        int a = (t >= off) ? sh[t - off] : 0;
        __syncthreads();
        sh[t] += a;
        __syncthreads();
    }
    if (i < NN) {
        rowptr[i] = sh[t] - v;
        dinv[i] = rsqrtf((float)(v + 1));   // deg = in-deg + self-loop
    }
    if (t == SCAN_BS - 1) bsum[blockIdx.x] = sh[t];
}

__global__ void k_scanB(int* __restrict__ bsum) {
    __shared__ int sh[256];
    int t = threadIdx.x;
    int v = (t < SCAN_NB) ? bsum[t] : 0;
    sh[t] = v;
    __syncthreads();
    for (int off = 1; off < 256; off <<= 1) {
        int a = (t >= off) ? sh[t - off] : 0;
        __syncthreads();
        sh[t] += a;
        __syncthreads();
    }
    if (t < SCAN_NB) bsum[t] = (t == 0) ? 0 : sh[t - 1];
}

__global__ void k_scanC(int* __restrict__ rowptr, const int* __restrict__ bsum,
                        int* __restrict__ cursor) {
    int i = blockIdx.x * SCAN_BS + threadIdx.x;
    if (i < NN) {
        int rp = rowptr[i] + bsum[blockIdx.x];
        rowptr[i] = rp;
        cursor[i] = rp;
    }
    if (i == 0) rowptr[NN] = NE;
}

// XCD-partitioned CSR scatter: group g writes only its 800KB ecol slice
__global__ void k_build(const int* __restrict__ src, const int* __restrict__ dst,
                        int* __restrict__ cursor, int* __restrict__ ecol) {
    int g = blockIdx.x & 7;
    int b = blockIdx.x >> 3;
    int lo = g * GRP_ROWS, hi = lo + GRP_ROWS;
    for (int e = b * blockDim.x + threadIdx.x; e < NE; e += BUILD_BPG * blockDim.x) {
        int d = dst[e];
        if (d >= lo && d < hi) {
            int pos = atomicAdd(&cursor[d], 1);
            ecol[pos] = src[e];
        }
    }
}

// xe = x[NN,16] @ W[16,64] + b
__global__ void k_embed(const float* __restrict__ x, const float* __restrict__ W,
                        const float* __restrict__ b, float* __restrict__ xe) {
    __shared__ float Ws[16 * 64];
    __shared__ float bs[64];
    int t = threadIdx.x;
    for (int i = t; i < 16 * 64; i += 256) Ws[i] = W[i];
    if (t < 64) bs[t] = b[t];
    __syncthreads();
    int c = t & 63, r = t >> 6;
    int n0 = blockIdx.x * 64;
    for (int n = n0 + r; n < n0 + 64 && n < NN; n += 4) {
        const float* xr = x + n * 16;
        float acc = bs[c];
#pragma unroll
        for (int k = 0; k < 16; k++) acc = fmaf(xr[k], Ws[k * 64 + c], acc);
        xe[n * 64 + c] = acc;
    }
}

// fused: xe += relu(agg*sc+sh) (prev BN, if apply); hwb = bf16(dinv*(xe@W))
__global__ void k_hw(const float* __restrict__ xeIn, float* __restrict__ xe,
                     const float* __restrict__ W, const float* __restrict__ dinv,
                     const float* __restrict__ agg, const float* __restrict__ ss,
                     unsigned short* __restrict__ hwb, double* __restrict__ sums,
                     int apply) {
    __shared__ float Ws[64 * 64];     // Ws[k][c]
    __shared__ float Xs[64 * 65];     // Xs[n][k], +1 pad
    int t = threadIdx.x;
    if (blockIdx.x == 0) {
        for (int i = t; i < 16 * 128; i += 256) sums[i] = 0.0;
    }
#pragma unroll
    for (int i = 0; i < 4; i++)
        ((float4*)Ws)[t + i * 256] = ((const float4*)W)[t + i * 256];
    int c = t & 63, rr = t >> 6;
    int n0 = blockIdx.x * 64;
#pragma unroll
    for (int i = 0; i < 16; i++) {
        int rl = i * 4 + rr;
        int n = n0 + rl;
        float xv = 0.f;
        if (n < NN) {
            xv = xeIn[n * 64 + c];
            if (apply) {
                float v = fmaf(agg[n * 64 + c], ss[c], ss[64 + c]);
                xv += fmaxf(v, 0.f);
                xe[n * 64 + c] = xv;
            }
        }
        Xs[rl * 65 + c] = xv;
    }
    __syncthreads();

    int r0 = (t >> 4) * 4, c0 = (t & 15) * 4;
    float acc[4][4];
#pragma unroll
    for (int a = 0; a < 4; a++)
#pragma unroll
        for (int b = 0; b < 4; b++) acc[a][b] = 0.f;
    for (int k = 0; k < 64; k++) {
        float4 wv = *(const float4*)&Ws[k * 64 + c0];
        float x0 = Xs[(r0 + 0) * 65 + k];
        float x1 = Xs[(r0 + 1) * 65 + k];
        float x2 = Xs[(r0 + 2) * 65 + k];
        float x3 = Xs[(r0 + 3) * 65 + k];
        acc[0][0] = fmaf(x0, wv.x, acc[0][0]); acc[0][1] = fmaf(x0, wv.y, acc[0][1]);
        acc[0][2] = fmaf(x0, wv.z, acc[0][2]); acc[0][3] = fmaf(x0, wv.w, acc[0][3]);
        acc[1][0] = fmaf(x1, wv.x, acc[1][0]); acc[1][1] = fmaf(x1, wv.y, acc[1][1]);
        acc[1][2] = fmaf(x1, wv.z, acc[1][2]); acc[1][3] = fmaf(x1, wv.w, acc[1][3]);
        acc[2][0] = fmaf(x2, wv.x, acc[2][0]); acc[2][1] = fmaf(x2, wv.y, acc[2][1]);
        acc[2][2] = fmaf(x2, wv.z, acc[2][2]); acc[2][3] = fmaf(x2, wv.w, acc[2][3]);
        acc[3][0] = fmaf(x3, wv.x, acc[3][0]); acc[3][1] = fmaf(x3, wv.y, acc[3][1]);
        acc[3][2] = fmaf(x3, wv.z, acc[3][2]); acc[3][3] = fmaf(x3, wv.w, acc[3][3]);
    }
#pragma unroll
    for (int a = 0; a < 4; a++) {
        int n = n0 + r0 + a;
        if (n < NN) {
            float di = dinv[n];
            float v0 = acc[a][0] * di, v1 = acc[a][1] * di;
            float v2 = acc[a][2] * di, v3 = acc[a][3] * di;
            uint2 pk;
            pk.x = ((unsigned)f2bf(v1) << 16) | f2bf(v0);
            pk.y = ((unsigned)f2bf(v3) << 16) | f2bf(v2);
            *(uint2*)(hwb + n * 64 + c0) = pk;
        }
    }
}

// agg[d] = dinv[d]*(hwb[d] + sum_{s in N(d)} hwb[s]); fused BN stats.
// Wave = 1 row; 4 groups of 16 lanes stride the edge list; lane q owns ch 4q..4q+3.
__global__ void k_spmm(const int* __restrict__ rowptr, const int* __restrict__ ecol,
                       const unsigned short* __restrict__ hwb, const float* __restrict__ dinv,
                       float* __restrict__ agg, double* __restrict__ sums) {
    int t = threadIdx.x;
    int w = t >> 6, l = t & 63;
    int grp = l >> 4, q = l & 15;
    const uint2* hw2 = (const uint2*)hwb;
    float ls0 = 0.f, ls1 = 0.f, ls2 = 0.f, ls3 = 0.f;
    float lq0 = 0.f, lq1 = 0.f, lq2 = 0.f, lq3 = 0.f;
    for (int row = blockIdx.x * 4 + w; row < NN; row += SPMM_BLOCKS * 4) {
        int p0 = __builtin_amdgcn_readfirstlane(rowptr[row]);
        int p1 = __builtin_amdgcn_readfirstlane(rowptr[row + 1]);
        uint2 sv = hw2[row * 16 + q];
        float a0 = 0.f, a1 = 0.f, a2 = 0.f, a3 = 0.f;
        int p = p0 + grp;
        for (; p + 12 < p1; p += 16) {   // unroll 4: 4 row-gathers in flight/group
            int s0 = ecol[p], s1 = ecol[p + 4], s2 = ecol[p + 8], s3 = ecol[p + 12];
            uint2 u0 = hw2[s0 * 16 + q];
            uint2 u1 = hw2[s1 * 16 + q];
            uint2 u2 = hw2[s2 * 16 + q];
            uint2 u3 = hw2[s3 * 16 + q];
            a0 += bflo(u0.x); a1 += bfhi(u0.x); a2 += bflo(u0.y); a3 += bfhi(u0.y);
            a0 += bflo(u1.x); a1 += bfhi(u1.x); a2 += bflo(u1.y); a3 += bfhi(u1.y);
            a0 += bflo(u2.x); a1 += bfhi(u2.x); a2 += bflo(u2.y); a3 += bfhi(u2.y);
            a0 += bflo(u3.x); a1 += bfhi(u3.x); a2 += bflo(u3.y); a3 += bfhi(u3.y);
        }
        for (; p < p1; p += 4) {
            int s0 = ecol[p];
            uint2 u0 = hw2[s0 * 16 + q];
            a0 += bflo(u0.x); a1 += bfhi(u0.x); a2 += bflo(u0.y); a3 += bfhi(u0.y);
        }
        a0 += __shfl_xor(a0, 16, 64); a0 += __shfl_xor(a0, 32, 64);
        a1 += __shfl_xor(a1, 16, 64); a1 += __shfl_xor(a1, 32, 64);
        a2 += __shfl_xor(a2, 16, 64); a2 += __shfl_xor(a2, 32, 64);
        a3 += __shfl_xor(a3, 16, 64); a3 += __shfl_xor(a3, 32, 64);
        float di = dinv[row];
        float v0 = (a0 + bflo(sv.x)) * di;
        float v1 = (a1 + bfhi(sv.x)) * di;
        float v2 = (a2 + bflo(sv.y)) * di;
        float v3 = (a3 + bfhi(sv.y)) * di;
        if (grp == 0) {
            float4 o = make_float4(v0, v1, v2, v3);
            *(float4*)(agg + row * 64 + 4 * q) = o;
        }
        ls0 += v0; ls1 += v1; ls2 += v2; ls3 += v3;
        lq0 = fmaf(v0, v0, lq0); lq1 = fmaf(v1, v1, lq1);
        lq2 = fmaf(v2, v2, lq2); lq3 = fmaf(v3, v3, lq3);
    }
    __shared__ float Ss[4][64], Sq[4][64];
    if (grp == 0) {
        Ss[w][4 * q + 0] = ls0; Ss[w][4 * q + 1] = ls1;
        Ss[w][4 * q + 2] = ls2; Ss[w][4 * q + 3] = ls3;
        Sq[w][4 * q + 0] = lq0; Sq[w][4 * q + 1] = lq1;
        Sq[w][4 * q + 2] = lq2; Sq[w][4 * q + 3] = lq3;
    }
    __syncthreads();
    if (t < 64) {
        float a = Ss[0][t] + Ss[1][t] + Ss[2][t] + Ss[3][t];
        float b = Sq[0][t] + Sq[1][t] + Sq[2][t] + Sq[3][t];
        double* sh = sums + (blockIdx.x & 15) * 128;
        atomicAdd(&sh[t], (double)a);
        atomicAdd(&sh[64 + t], (double)b);
    }
}

__global__ void k_finalize(const double* __restrict__ sums, const float* __restrict__ gamma,
                           const float* __restrict__ beta, float* __restrict__ ss) {
    int c = threadIdx.x;  // 64 threads
    double s = 0.0, q = 0.0;
#pragma unroll
    for (int k = 0; k < 16; k++) { s += sums[k * 128 + c]; q += sums[k * 128 + 64 + c]; }
    double mean = s / (double)NN;
    double var = q / (double)NN - mean * mean;
    float sc = gamma[c] * rsqrtf((float)var + BN_EPS);
    ss[c] = sc;
    ss[64 + c] = beta[c] - (float)mean * sc;
}

// final layer: xe += relu(agg*scale + shift)
__global__ void k_apply(const float* __restrict__ agg, const float* __restrict__ ss,
                        float* __restrict__ xe) {
    int i = blockIdx.x * blockDim.x + threadIdx.x;
    if (i < NN * HID) {
        int c = i & 63;
        float v = fmaf(agg[i], ss[c], ss[64 + c]);
        xe[i] += fmaxf(v, 0.f);
    }
}

// out[e] = [xe[s]; xe[d]] @ fc_W + fc_b
__global__ void k_out(const int* __restrict__ esrc, const int* __restrict__ edst,
                      const float* __restrict__ xe, const float* __restrict__ fcW,
                      const float* __restrict__ fcb, float* __restrict__ out) {
    __shared__ float Ws[256];
    __shared__ float bs[2];
    int t = threadIdx.x;
    for (int i = t; i < 256; i += 256) Ws[i] = fcW[i];
    if (t < 2) bs[t] = fcb[t];
    __syncthreads();
    int e = blockIdx.x * blockDim.x + t;
    if (e < NEO) {
        int s = esrc[e], d = edst[e];
        const float4* rs = (const float4*)(xe + s * 64);
        const float4* rd = (const float4*)(xe + d * 64);
        float a0 = bs[0], a1 = bs[1];
#pragma unroll
        for (int i = 0; i < 16; i++) {
            float4 v = rs[i];
            a0 += v.x * Ws[(i * 4 + 0) * 2] + v.y * Ws[(i * 4 + 1) * 2] +
                  v.z * Ws[(i * 4 + 2) * 2] + v.w * Ws[(i * 4 + 3) * 2];
            a1 += v.x * Ws[(i * 4 + 0) * 2 + 1] + v.y * Ws[(i * 4 + 1) * 2 + 1] +
                  v.z * Ws[(i * 4 + 2) * 2 + 1] + v.w * Ws[(i * 4 + 3) * 2 + 1];
        }
#pragma unroll
        for (int i = 0; i < 16; i++) {
            float4 v = rd[i];
            a0 += v.x * Ws[(64 + i * 4 + 0) * 2] + v.y * Ws[(64 + i * 4 + 1) * 2] +
                  v.z * Ws[(64 + i * 4 + 2) * 2] + v.w * Ws[(64 + i * 4 + 3) * 2];
            a1 += v.x * Ws[(64 + i * 4 + 0) * 2 + 1] + v.y * Ws[(64 + i * 4 + 1) * 2 + 1] +
                  v.z * Ws[(64 + i * 4 + 2) * 2 + 1] + v.w * Ws[(64 + i * 4 + 3) * 2 + 1];
        }
        out[e * 2] = a0;
        out[e * 2 + 1] = a1;
    }
}

extern "C" void kernel_launch(void* const* d_in, const int* in_sizes, int n_in,
                              void* d_out, int out_size, void* d_ws, size_t ws_size,
                              hipStream_t stream) {
    const float* x      = (const float*)d_in[0];
    const int*   ei     = (const int*)d_in[1];
    const int*   eio    = (const int*)d_in[2];
    const float* W_emb  = (const float*)d_in[3];
    const float* b_emb  = (const float*)d_in[4];
    const float* conv_W = (const float*)d_in[5];
    // d_in[6] conv_b: cancels inside BN
    const float* bn_g   = (const float*)d_in[7];
    const float* bn_b   = (const float*)d_in[8];
    const float* fc_W   = (const float*)d_in[9];
    const float* fc_b   = (const float*)d_in[10];
    float* out = (float*)d_out;

    float* ws   = (float*)d_ws;
    int*   ecol = (int*)(ws + OFF_ECOL);
    float* xe   = ws + OFF_XE;
    float* agg  = ws + OFF_AGG;
    unsigned short* hwb = (unsigned short*)(ws + OFF_HWB);

    float* od     = (float*)d_out;
    float* dinv   = od + OD_DINV;
    int*   rowptr = (int*)(od + OD_ROWPTR);
    int*   cc     = (int*)(od + OD_CC);
    int*   bsum   = (int*)(od + OD_BSUM);
    float* ss     = od + OD_SS;
    double* sums  = (double*)(od + OD_SUMS);

    const int* src  = ei;
    const int* dst  = ei + NE;
    const int* esrc = eio;
    const int* edst = eio + NEO;

    // ---- one-time CSR build (XCD-partitioned hist + scatter) ----
    hipMemsetAsync(cc, 0, NN * sizeof(int), stream);
    k_hist<<<8 * BUILD_BPG, 256, 0, stream>>>(dst, cc);
    k_scanA<<<SCAN_NB, SCAN_BS, 0, stream>>>(cc, rowptr, bsum, dinv);
    k_scanB<<<1, 256, 0, stream>>>(bsum);
    k_scanC<<<SCAN_NB, SCAN_BS, 0, stream>>>(rowptr, bsum, cc);
    k_build<<<8 * BUILD_BPG, 256, 0, stream>>>(src, dst, cc, ecol);

    k_embed<<<(NN + 63) / 64, 256, 0, stream>>>(x, W_emb, b_emb, xe);

    for (int l = 0; l < NL; l++) {
        k_hw<<<(NN + 63) / 64, 256, 0, stream>>>(xe, xe, conv_W + l * 64 * 64, dinv,
                                                 agg, ss, hwb, sums, l > 0 ? 1 : 0);
        k_spmm<<<SPMM_BLOCKS, 256, 0, stream>>>(rowptr, ecol, hwb, dinv, agg, sums);
        k_finalize<<<1, 64, 0, stream>>>(sums, bn_g + l * 64, bn_b + l * 64, ss);
    }
    k_apply<<<(NN * HID) / 256, 256, 0, stream>>>(agg, ss, xe);

    k_out<<<(NEO + 255) / 256, 256, 0, stream>>>(esrc, edst, xe, fc_W, fc_b, out);
}